// Round 10
// baseline (181.692 us; speedup 1.0000x reference)
//
#include <hip/hip_runtime.h>
#include <stdint.h>

#define NROWS 16384   // 16*32*32 spatial positions
#define NCODES 8192
#define DIM 256
// score = 1024 + dot - ||e||^2/2  (higher = closer). bf16 dist-error sigma
// ~0.05 in score units. EPS_S = 0.4 (8 sigma one-sided, validated absmax=0
// across both sessions). SM = 0.5 (7.1 sigma on the gap diff; validated R9).
// R8 f16 lesson: margins are validated AGAINST the bf16 error model; dtype
// swaps change the model and void the validation. bf16 is frozen.
#define EPS_S 0.4f
#define SM 0.5f

typedef __attribute__((ext_vector_type(8))) short bf16x8;    // 8 bf16 = 4 VGPRs
typedef __attribute__((ext_vector_type(16))) float f32x16;   // 32x32 C/D frag
typedef unsigned int uint32;

__device__ __forceinline__ unsigned short f2bf(float f) {
  union { float f; unsigned int u; } v; v.f = f;
  unsigned int u = v.u;
  return (unsigned short)((u + 0x7FFFu + ((u >> 16) & 1u)) >> 16);  // RNE
}

// exact-path u64 key = order-preserving dist bits << 32 | idx (min = best+lowest idx)
__device__ __forceinline__ unsigned long long packdi(float d, int idx) {
  unsigned int u = __float_as_uint(d);
  u = (u & 0x80000000u) ? ~u : (u | 0x80000000u);
  return ((unsigned long long)u << 32) | (unsigned int)idx;
}
__device__ __forceinline__ unsigned long long u64min(unsigned long long a,
                                                     unsigned long long b) {
  return a < b ? a : b;
}
__device__ __forceinline__ unsigned long long shflx64(unsigned long long v, int m) {
  int lo = __shfl_xor((int)(unsigned int)v, m);
  int hi = __shfl_xor((int)(v >> 32), m);
  return ((unsigned long long)(unsigned int)hi << 32) | (unsigned int)lo;
}
__device__ __forceinline__ uint32 umax(uint32 a, uint32 b) { return a > b ? a : b; }
__device__ __forceinline__ uint32 umin(uint32 a, uint32 b) { return a < b ? a : b; }

// async global->LDS, 16B per lane; LDS dest is wave-uniform base + lane*16
__device__ __forceinline__ void glds16(const ushort* g, ushort* l) {
  __builtin_amdgcn_global_load_lds(
      (const __attribute__((address_space(1))) unsigned int*)g,
      (__attribute__((address_space(3))) unsigned int*)l, 16, 0, 0);
}

// ---- Phase 0 (fused): z transpose+bf16, codebook bf16+norms ----------------
// R10 delta: the post-transpose stores were SCALAR (4 B flatz + 2 B zb per
// lane -- Common-mistake #2, invisible all session because prep never made
// top-5). Now thread (r = tid>>3, q = tid&7) reads 4 channels from LDS
// (t[q*4+j][r]; 33-pad -> uniform 2-way bank aliasing = free) and writes one
// float4 + one ushort4. Output bytes identical (same f2bf, same addresses).
__global__ __launch_bounds__(256) void prep(const float* __restrict__ z,
                                            const float* __restrict__ cb,
                                            float* __restrict__ flatz,
                                            ushort* __restrict__ zb,
                                            ushort* __restrict__ eb,
                                            float* __restrict__ enorm) {
  __shared__ float t[32][33];
  const int blk = blockIdx.x;
  if (blk < 4096) {  // prep_z part: NCHW -> (row, d), fp32 copy into zq
    const int tx = threadIdx.x & 31, ty = threadIdx.x >> 5;  // 32 x 8 loads
    const int ht = blk & 31, ct = (blk >> 5) & 7, b = blk >> 8;
    const float* src = z + (size_t)b * 262144 + (size_t)(ct * 32) * 1024 + ht * 32;
#pragma unroll
    for (int i = 0; i < 4; ++i) {
      int c = ty + i * 8;
      t[c][tx] = src[c * 1024 + tx];
    }
    __syncthreads();
    const int r = threadIdx.x >> 3, q = threadIdx.x & 7;  // row r, chan quad q
    float4 vv;
    vv.x = t[q * 4 + 0][r];
    vv.y = t[q * 4 + 1][r];
    vv.z = t[q * 4 + 2][r];
    vv.w = t[q * 4 + 3][r];
    const int row = b * 1024 + ht * 32 + r;
    *(float4*)(flatz + (size_t)row * 256 + ct * 32 + q * 4) = vv;
    ushort4 o;
    o.x = f2bf(vv.x); o.y = f2bf(vv.y); o.z = f2bf(vv.z); o.w = f2bf(vv.w);
    *(ushort4*)(zb + (size_t)row * 256 + ct * 32 + q * 4) = o;
  } else {  // prep_cb part
    const int lane = threadIdx.x & 63, wave = threadIdx.x >> 6;
    const int code = (blk - 4096) * 4 + wave;
    float4 v = *(const float4*)(cb + (size_t)code * 256 + lane * 4);
    ushort4 o;
    o.x = f2bf(v.x); o.y = f2bf(v.y); o.z = f2bf(v.z); o.w = f2bf(v.w);
    *(ushort4*)(eb + (size_t)code * 256 + lane * 4) = o;
    float ss = v.x * v.x + v.y * v.y + v.z * v.z + v.w * v.w;
#pragma unroll
    for (int s = 1; s < 64; s <<= 1) ss += __shfl_xor(ss, s);
    if (lane == 0) enorm[code] = ss;
  }
}

// acc init for output-tile ot: 1024 - 0.5*||e||^2 through the 32x32 C/D
// layout (reg p covers code row (p&3)+8*(p>>2)+4*lg of frag m  [m74/m101]).
__device__ __forceinline__ void init_acc(f32x16 acc[4][2], const float* en,
                                         int ot, int wm, int lg) {
#pragma unroll
  for (int m = 0; m < 4; ++m) {
    const float* ep = en + ot * 256 + wm * 128 + m * 32 + 4 * lg;
    float4 e0 = *(const float4*)(ep);
    float4 e1 = *(const float4*)(ep + 8);
    float4 e2 = *(const float4*)(ep + 16);
    float4 e3 = *(const float4*)(ep + 24);
    f32x16 c0;
    c0[0]  = 1024.f - 0.5f * e0.x; c0[1]  = 1024.f - 0.5f * e0.y;
    c0[2]  = 1024.f - 0.5f * e0.z; c0[3]  = 1024.f - 0.5f * e0.w;
    c0[4]  = 1024.f - 0.5f * e1.x; c0[5]  = 1024.f - 0.5f * e1.y;
    c0[6]  = 1024.f - 0.5f * e1.z; c0[7]  = 1024.f - 0.5f * e1.w;
    c0[8]  = 1024.f - 0.5f * e2.x; c0[9]  = 1024.f - 0.5f * e2.y;
    c0[10] = 1024.f - 0.5f * e2.z; c0[11] = 1024.f - 0.5f * e2.w;
    c0[12] = 1024.f - 0.5f * e3.x; c0[13] = 1024.f - 0.5f * e3.y;
    c0[14] = 1024.f - 0.5f * e3.z; c0[15] = 1024.f - 0.5f * e3.w;
    acc[m][0] = c0; acc[m][1] = c0;
  }
}

// epilogue for output-tile ot (validated logic): per (m,n,hc) frag-chunk of
// 16 codes, lane holds 8 regs (hc*8+p), id = (p&3) | lg<<2 | (p>>2)<<3.
// Top-2 via u32 chains + one cross-lane (lg) merge; flag bit 4 = gap > SM.
__device__ __forceinline__ void epilogue(const f32x16 acc[4][2],
                                         uint32* __restrict__ bm, int cg,
                                         int ot, int zrow0, int wm, int wn,
                                         int l31, int lg) {
  const int cid0 = cg * 128 + ot * 16 + wm * 8;
#pragma unroll
  for (int n = 0; n < 2; ++n) {
    uint32 res[8];
#pragma unroll
    for (int m = 0; m < 4; ++m)
#pragma unroll
      for (int hc = 0; hc < 2; ++hc) {
        uint32 m1 = 0, m2 = 0;
#pragma unroll
        for (int p = 0; p < 8; ++p) {
          uint32 id = (uint32)((p & 3) | (lg << 2) | ((p >> 2) << 3));
          uint32 pv = (__float_as_uint(acc[m][n][hc * 8 + p]) & ~31u) | id;
          m2 = umax(m2, umin(m1, pv));
          m1 = umax(m1, pv);
        }
        uint32 o1 = (uint32)__shfl_xor((int)m1, 32);
        uint32 o2 = (uint32)__shfl_xor((int)m2, 32);
        m2 = umax(umax(m2, o2), umin(m1, o1));
        m1 = umax(m1, o1);
        float s1 = __uint_as_float(m1 & ~31u);
        float s2 = __uint_as_float(m2 & ~31u);
        res[m * 2 + hc] = (s1 - s2 > SM) ? (m1 | 16u) : m1;
      }
    const int zr = zrow0 + wn * 64 + n * 32 + l31;
    uint4 o;  // lg half 0 writes chunks 0..3, half 1 writes 4..7
    o.x = lg ? res[4] : res[0];
    o.y = lg ? res[5] : res[1];
    o.z = lg ? res[6] : res[2];
    o.w = lg ? res[7] : res[3];
    *(uint4*)(bm + (size_t)zr * 512 + cid0 + lg * 4) = o;
  }
}

// ---- Phase 1: bf16 MFMA score GEMM — R3 ring verbatim (validated best) -----
// Persistent ring, depth-3 prefetch, floor swizzle. Gemm frozen as control:
// R4 (ordering) and R7 (occupancy) falsified the other structural theories;
// this is the measured optimum of the decomposition (~92 us).
__global__ __launch_bounds__(512, 2) void vq_gemm(const ushort* __restrict__ eb,
                                                  const ushort* __restrict__ zb,
                                                  const float* __restrict__ enorm,
                                                  uint32* __restrict__ bm) {
  __shared__ __align__(16) ushort As[4 * 8192];  // 4 slots x (256 rows x 32 k)
  __shared__ __align__(16) ushort Bs[4 * 8192];  // 64 KB + 64 KB
  __shared__ __align__(16) float en[2048];       // 8 KB enorm slice
  const int tid = threadIdx.x;
  const int wave = tid >> 6, lane = tid & 63;
  const int wm = wave >> 2, wn = wave & 3;  // wave tile: 128 codes x 64 zrows
  const int l31 = lane & 31, lg = lane >> 5;
  const int y = blockIdx.x & 63, cg = blockIdx.x >> 6;  // y%8 -> XCD locality
  const int code00 = cg * 2048;   // block's 8 code panels: code00 + ot*256
  const int zrow0 = y * 256;

  // enorm slice -> LDS (plain loads; drained by the syncthreads below)
  *(float4*)&en[tid * 4] = *(const float4*)(enorm + code00 + tid * 4);
  __syncthreads();

  // staging: chunk = 1024 16B-units per matrix; unit u: row = u>>2,
  // lds-slot = u&3, global k-group = (u&3) ^ ((u>>3)&3)  [= slot^((row>>1)&3)].
  // Thread stages units tid and tid+512 of each matrix (4 glds/chunk).
  const int u0 = tid, u1 = tid + 512;
  const ushort* aU0 = eb + (size_t)(code00 + (u0 >> 2)) * 256 +
                      ((u0 & 3) ^ ((u0 >> 3) & 3)) * 8;
  const ushort* aU1 = eb + (size_t)(code00 + (u1 >> 2)) * 256 +
                      ((u1 & 3) ^ ((u1 >> 3) & 3)) * 8;
  const ushort* bU0 = zb + (size_t)(zrow0 + (u0 >> 2)) * 256 +
                      ((u0 & 3) ^ ((u0 >> 3) & 3)) * 8;
  const ushort* bU1 = zb + (size_t)(zrow0 + (u1 >> 2)) * 256 +
                      ((u1 & 3) ^ ((u1 >> 3) & 3)) * 8;
  ushort* aL = As + wave * 512;  // + slot*8192 (+4096 for unit1); lane*16B is HW
  ushort* bL = Bs + wave * 512;

  // prologue: issue chunks 0,1,2 (panel 0, koff = c*32)
#pragma unroll
  for (int c = 0; c < 3; ++c) {
    glds16(aU0 + c * 32, aL + c * 8192);
    glds16(aU1 + c * 32, aL + c * 8192 + 4096);
    glds16(bU0 + c * 32, bL + c * 8192);
    glds16(bU1 + c * 32, bL + c * 8192 + 4096);
  }

  f32x16 acc[4][2];
  init_acc(acc, en, 0, wm, lg);

  asm volatile("s_waitcnt vmcnt(8)" ::: "memory");  // chunk 0 resident
  __builtin_amdgcn_s_barrier();
  asm volatile("" ::: "memory");

  // frag read addressing: row = base + l31; k-group g lives at swizzled slot
  // g ^ ((row>>1)&3) = g ^ ((l31>>1)&3). Frag ks needs g = 2*ks + lg.
  const int swz = (l31 >> 1) & 3;
  const int colu0 = ((0 | lg) ^ swz) * 8;   // ks=0
  const int colu1 = ((2 | lg) ^ swz) * 8;   // ks=1
  const int arow_u = (wm * 128 + l31) * 32;
  const int brow_u = (wn * 64 + l31) * 32;

#pragma unroll 1
  for (int ot = 0; ot < 8; ++ot) {
    if (ot > 0) {  // finish previous tile while chunk stream stays in flight
      epilogue(acc, bm, cg, ot - 1, zrow0, wm, wn, l31, lg);
      init_acc(acc, en, ot, wm, lg);
    }
#pragma unroll
    for (int cc = 0; cc < 8; ++cc) {
      const int slot = cc & 3;
      // 1) issue chunk c+3 (c = ot*8+cc; valid while c <= 60)
      if (ot < 7 || cc <= 4) {
        const int s2 = (cc + 3) & 3;
        const size_t off = (size_t)((cc + 3) >> 3) * 65536 +
                           (size_t)ot * 65536 + ((cc + 3) & 7) * 32;
        const size_t boff = ((cc + 3) & 7) * 32;  // B panel fixed; k cycles
        glds16(aU0 + off, aL + s2 * 8192);
        glds16(aU1 + off, aL + s2 * 8192 + 4096);
        glds16(bU0 + boff, bL + s2 * 8192);
        glds16(bU1 + boff, bL + s2 * 8192 + 4096);
      }
      // 2) ds_read 12 frags of chunk c (resident per previous barrier)
      bf16x8 a0[4], a1[4], b0[2], b1[2];
#pragma unroll
      for (int m = 0; m < 4; ++m) {
        a0[m] = *(const bf16x8*)&As[slot * 8192 + arow_u + m * 1024 + colu0];
        a1[m] = *(const bf16x8*)&As[slot * 8192 + arow_u + m * 1024 + colu1];
      }
#pragma unroll
      for (int n = 0; n < 2; ++n) {
        b0[n] = *(const bf16x8*)&Bs[slot * 8192 + brow_u + n * 1024 + colu0];
        b1[n] = *(const bf16x8*)&Bs[slot * 8192 + brow_u + n * 1024 + colu1];
      }
      // 3) 16 MFMA (compiler interleaves lgkmcnt(N) with the reads above)
      __builtin_amdgcn_s_setprio(1);
#pragma unroll
      for (int m = 0; m < 4; ++m)
#pragma unroll
        for (int n = 0; n < 2; ++n)
          acc[m][n] = __builtin_amdgcn_mfma_f32_32x32x16_bf16(a0[m], b0[n],
                                                              acc[m][n], 0, 0, 0);
#pragma unroll
      for (int m = 0; m < 4; ++m)
#pragma unroll
        for (int n = 0; n < 2; ++n)
          acc[m][n] = __builtin_amdgcn_mfma_f32_32x32x16_bf16(a1[m], b1[n],
                                                              acc[m][n], 0, 0, 0);
      __builtin_amdgcn_s_setprio(0);
      // 4) counted wait for chunk c+1 (+ barrier). Steady: 3 chunk-groups
      // (12 glds) outstanding -> vmcnt(8). Tail: 61 -> 4, 62 -> 0, 63: none.
      if (ot < 7 || cc <= 4) {
        asm volatile("s_waitcnt vmcnt(8)" ::: "memory");
        __builtin_amdgcn_s_barrier();
        asm volatile("" ::: "memory");
      } else if (cc == 5) {
        asm volatile("s_waitcnt vmcnt(4)" ::: "memory");
        __builtin_amdgcn_s_barrier();
        asm volatile("" ::: "memory");
      } else if (cc == 6) {
        asm volatile("s_waitcnt vmcnt(0)" ::: "memory");
        __builtin_amdgcn_s_barrier();
        asm volatile("" ::: "memory");
      }  // cc == 7 of ot == 7: last phase, fall through to epilogue
    }
  }
  epilogue(acc, bm, cg, 7, zrow0, wm, wn, l31, lg);
}

// exact fp32 distances for one 16-code chunk; summation order / lane split /
// tie-break bit-identical to the validated slow path.
__device__ __forceinline__ unsigned long long chunk_exact(
    int chunk, const float* __restrict__ zrow, const float* __restrict__ cb,
    const float* __restrict__ enorm, int lane) {
  const int code = chunk * 16 + (lane >> 2);
  const float* zp = zrow + (lane & 3) * 64;
  const float* cp = cb + (size_t)code * 256 + (lane & 3) * 64;
  float s = 0.f;
#pragma unroll
  for (int d = 0; d < 64; d += 4) {
    float4 zv = *(const float4*)(zp + d);
    float4 cv = *(const float4*)(cp + d);
    s = fmaf(zv.x, cv.x, s); s = fmaf(zv.y, cv.y, s);
    s = fmaf(zv.z, cv.z, s); s = fmaf(zv.w, cv.w, s);
  }
  s += __shfl_xor(s, 1);
  s += __shfl_xor(s, 2);
  float dist = fmaf(-2.f, s, enorm[code]);
  unsigned long long key = ((lane & 3) == 0) ? packdi(dist, code) : ~0ull;
#pragma unroll
  for (int m = 1; m < 64; m <<= 1) key = u64min(key, shflx64(key, m));
  return key;  // wave-uniform
}

// ---- Phase 2: one wave per row over 512 chunk16 maxima (validated verbatim) -
__global__ __launch_bounds__(256) void vq_sel(const uint32* __restrict__ bm,
                                              const float* __restrict__ flatz,
                                              const float* __restrict__ cb,
                                              const float* __restrict__ enorm,
                                              float* __restrict__ zq,
                                              float* __restrict__ oidx) {
  const int lane = threadIdx.x & 63;
  const int row = blockIdx.x * 4 + (threadIdx.x >> 6);
  uint4 va = *(const uint4*)(bm + (size_t)row * 512 + lane * 8);
  uint4 vb = *(const uint4*)(bm + (size_t)row * 512 + lane * 8 + 4);
  uint32 v[8] = {va.x, va.y, va.z, va.w, vb.x, vb.y, vb.z, vb.w};
  uint32 m1 = 0, m2 = 0; int ch = 0;
#pragma unroll
  for (int s = 0; s < 8; ++s) {
    uint32 pv = v[s];
    m2 = umax(m2, umin(m1, pv));
    ch = (pv > m1) ? (lane * 8 + s) : ch;
    m1 = umax(m1, pv);
  }
#pragma unroll
  for (int m = 1; m < 64; m <<= 1) {
    uint32 o1 = (uint32)__shfl_xor((int)m1, m);
    uint32 o2 = (uint32)__shfl_xor((int)m2, m);
    int oc = __shfl_xor(ch, m);
    m2 = umax(umax(m2, o2), umin(m1, o1));
    ch = (o1 > m1) ? oc : ch;
    m1 = umax(m1, o1);
  }
  // all wave-uniform now
  float s1 = __uint_as_float(m1 & ~31u);
  float s2 = __uint_as_float(m2 & ~31u);
  int idx;
  if ((m1 & 16u) && (s1 - s2 > SM)) {
    idx = ch * 16 + (int)(m1 & 15u);  // provably the exact argmin
  } else {
    const float* zrow = flatz + (size_t)row * 256;
    unsigned long long key = chunk_exact(ch, zrow, cb, enorm, lane);
    float dbest;
    { unsigned int u = (unsigned int)(key >> 32);
      u = (u & 0x80000000u) ? (u & 0x7FFFFFFFu) : ~u;
      dbest = __uint_as_float(u); }
    float thr = (1024.f - 0.5f * dbest) - EPS_S;  // window lower bound
#pragma unroll
    for (int s = 0; s < 8; ++s) {
      bool cand = __uint_as_float(v[s] & ~31u) >= thr;
      unsigned long long mk = __ballot(cand);
      while (mk) {
        int L = __ffsll(mk) - 1;
        mk &= mk - 1;
        int c2 = L * 8 + s;
        if (c2 == ch) continue;
        key = u64min(key, chunk_exact(c2, zrow, cb, enorm, lane));
      }
    }
    idx = (int)(key & 0xFFFFFFFFull);
  }
  if (lane == 0) oidx[row] = (float)idx;
  float4 val = *(const float4*)(cb + (size_t)idx * 256 + lane * 4);
  *(float4*)(zq + (size_t)row * 256 + lane * 4) = val;  // exact fp32 gather
}

// ---- launch ----------------------------------------------------------------
extern "C" void kernel_launch(void* const* d_in, const int* in_sizes, int n_in,
                              void* d_out, int out_size, void* d_ws, size_t ws_size,
                              hipStream_t stream) {
  const float* z = (const float*)d_in[0];   // (16,256,32,32) fp32
  const float* cb = (const float*)d_in[1];  // (8192,256) fp32
  char* ws = (char*)d_ws;
  // ws: zb 8M@0 | eb 4M@8M | enorm 32K@12M | bm 32M@13M  (45 MB, proven fit)
  ushort* zb = (ushort*)(ws);
  ushort* eb = (ushort*)(ws + (8u << 20));
  float* enorm = (float*)(ws + (12u << 20));
  uint32* bm = (uint32*)(ws + (13u << 20));
  float* zq = (float*)d_out;               // (16384,256) fp32
  float* oidx = zq + (size_t)NROWS * DIM;  // (16384,) as fp32 values
  float* flatz = zq;  // NHWC fp32 z lives in zq until vq_sel overwrites per-row

  prep<<<4096 + NCODES / 4, 256, 0, stream>>>(z, cb, flatz, zb, eb, enorm);
  vq_gemm<<<256, 512, 0, stream>>>(eb, zb, enorm, bm);
  vq_sel<<<NROWS / 4, 256, 0, stream>>>(bm, flatz, cb, enorm, zq, oidx);
}

// Round 11
// 177.314 us; speedup vs baseline: 1.0247x; 1.0247x over previous
//
#include <hip/hip_runtime.h>
#include <stdint.h>

#define NROWS 16384   // 16*32*32 spatial positions
#define NCODES 8192
#define DIM 256
// score = 1024 + dot - ||e||^2/2  (higher = closer). bf16 dist-error sigma
// ~0.05 in score units. EPS_S = 0.4 (8 sigma one-sided, validated absmax=0
// across both sessions). SM = 0.5 (7.1 sigma on the gap diff; validated R9).
// R8 f16 lesson: margins are validated AGAINST the bf16 error model; dtype
// swaps change the model and void the validation. bf16 is frozen.
#define EPS_S 0.4f
#define SM 0.5f

typedef __attribute__((ext_vector_type(8))) short bf16x8;    // 8 bf16 = 4 VGPRs
typedef __attribute__((ext_vector_type(16))) float f32x16;   // 32x32 C/D frag
typedef unsigned int uint32;

__device__ __forceinline__ unsigned short f2bf(float f) {
  union { float f; unsigned int u; } v; v.f = f;
  unsigned int u = v.u;
  return (unsigned short)((u + 0x7FFFu + ((u >> 16) & 1u)) >> 16);  // RNE
}

// exact-path u64 key = order-preserving dist bits << 32 | idx (min = best+lowest idx)
__device__ __forceinline__ unsigned long long packdi(float d, int idx) {
  unsigned int u = __float_as_uint(d);
  u = (u & 0x80000000u) ? ~u : (u | 0x80000000u);
  return ((unsigned long long)u << 32) | (unsigned int)idx;
}
__device__ __forceinline__ unsigned long long u64min(unsigned long long a,
                                                     unsigned long long b) {
  return a < b ? a : b;
}
__device__ __forceinline__ unsigned long long shflx64(unsigned long long v, int m) {
  int lo = __shfl_xor((int)(unsigned int)v, m);
  int hi = __shfl_xor((int)(v >> 32), m);
  return ((unsigned long long)(unsigned int)hi << 32) | (unsigned int)lo;
}
__device__ __forceinline__ uint32 umax(uint32 a, uint32 b) { return a > b ? a : b; }
__device__ __forceinline__ uint32 umin(uint32 a, uint32 b) { return a < b ? a : b; }

// async global->LDS, 16B per lane; LDS dest is wave-uniform base + lane*16
__device__ __forceinline__ void glds16(const ushort* g, ushort* l) {
  __builtin_amdgcn_global_load_lds(
      (const __attribute__((address_space(1))) unsigned int*)g,
      (__attribute__((address_space(3))) unsigned int*)l, 16, 0, 0);
}

// ---- Phase 0 (fused): z transpose+bf16, codebook bf16+norms ----------------
// R10's vectorized post-transpose stores (float4 + ushort4), validated.
__global__ __launch_bounds__(256) void prep(const float* __restrict__ z,
                                            const float* __restrict__ cb,
                                            float* __restrict__ flatz,
                                            ushort* __restrict__ zb,
                                            ushort* __restrict__ eb,
                                            float* __restrict__ enorm) {
  __shared__ float t[32][33];
  const int blk = blockIdx.x;
  if (blk < 4096) {  // prep_z part: NCHW -> (row, d), fp32 copy into zq
    const int tx = threadIdx.x & 31, ty = threadIdx.x >> 5;  // 32 x 8 loads
    const int ht = blk & 31, ct = (blk >> 5) & 7, b = blk >> 8;
    const float* src = z + (size_t)b * 262144 + (size_t)(ct * 32) * 1024 + ht * 32;
#pragma unroll
    for (int i = 0; i < 4; ++i) {
      int c = ty + i * 8;
      t[c][tx] = src[c * 1024 + tx];
    }
    __syncthreads();
    const int r = threadIdx.x >> 3, q = threadIdx.x & 7;  // row r, chan quad q
    float4 vv;
    vv.x = t[q * 4 + 0][r];
    vv.y = t[q * 4 + 1][r];
    vv.z = t[q * 4 + 2][r];
    vv.w = t[q * 4 + 3][r];
    const int row = b * 1024 + ht * 32 + r;
    *(float4*)(flatz + (size_t)row * 256 + ct * 32 + q * 4) = vv;
    ushort4 o;
    o.x = f2bf(vv.x); o.y = f2bf(vv.y); o.z = f2bf(vv.z); o.w = f2bf(vv.w);
    *(ushort4*)(zb + (size_t)row * 256 + ct * 32 + q * 4) = o;
  } else {  // prep_cb part
    const int lane = threadIdx.x & 63, wave = threadIdx.x >> 6;
    const int code = (blk - 4096) * 4 + wave;
    float4 v = *(const float4*)(cb + (size_t)code * 256 + lane * 4);
    ushort4 o;
    o.x = f2bf(v.x); o.y = f2bf(v.y); o.z = f2bf(v.z); o.w = f2bf(v.w);
    *(ushort4*)(eb + (size_t)code * 256 + lane * 4) = o;
    float ss = v.x * v.x + v.y * v.y + v.z * v.z + v.w * v.w;
#pragma unroll
    for (int s = 1; s < 64; s <<= 1) ss += __shfl_xor(ss, s);
    if (lane == 0) enorm[code] = ss;
  }
}

// acc init: 1024 - 0.5*||e||^2 through the 32x32 C/D layout (reg p covers
// code row (p&3)+8*(p>>2)+4*lg of frag m  [m74/m101]). epb = enorm + code0
// (GLOBAL; block's codes fixed, values L2-hot after first panel). The loads
// are VMEM and only OVER-count the phase-end vmcnt(0) (safe: waits more).
__device__ __forceinline__ void init_acc(f32x16 acc[4][2],
                                         const float* __restrict__ epb,
                                         int wm, int lg) {
#pragma unroll
  for (int m = 0; m < 4; ++m) {
    const float* ep = epb + wm * 128 + m * 32 + 4 * lg;
    float4 e0 = *(const float4*)(ep);
    float4 e1 = *(const float4*)(ep + 8);
    float4 e2 = *(const float4*)(ep + 16);
    float4 e3 = *(const float4*)(ep + 24);
    f32x16 c0;
    c0[0]  = 1024.f - 0.5f * e0.x; c0[1]  = 1024.f - 0.5f * e0.y;
    c0[2]  = 1024.f - 0.5f * e0.z; c0[3]  = 1024.f - 0.5f * e0.w;
    c0[4]  = 1024.f - 0.5f * e1.x; c0[5]  = 1024.f - 0.5f * e1.y;
    c0[6]  = 1024.f - 0.5f * e1.z; c0[7]  = 1024.f - 0.5f * e1.w;
    c0[8]  = 1024.f - 0.5f * e2.x; c0[9]  = 1024.f - 0.5f * e2.y;
    c0[10] = 1024.f - 0.5f * e2.z; c0[11] = 1024.f - 0.5f * e2.w;
    c0[12] = 1024.f - 0.5f * e3.x; c0[13] = 1024.f - 0.5f * e3.y;
    c0[14] = 1024.f - 0.5f * e3.z; c0[15] = 1024.f - 0.5f * e3.w;
    acc[m][0] = c0; acc[m][1] = c0;
  }
}

// epilogue (validated logic verbatim): per (m,n,hc) frag-chunk of 16 codes,
// lane holds 8 regs (hc*8+p), id = (p&3) | lg<<2 | (p>>2)<<3. Top-2 via u32
// chains + one cross-lane (lg) merge; flag bit 4 = gap > SM.
__device__ __forceinline__ void epilogue(const f32x16 acc[4][2],
                                         uint32* __restrict__ bm, int cid0b,
                                         int zrowb, int wm, int wn,
                                         int l31, int lg) {
  const int cid0 = cid0b + wm * 8;
#pragma unroll
  for (int n = 0; n < 2; ++n) {
    uint32 res[8];
#pragma unroll
    for (int m = 0; m < 4; ++m)
#pragma unroll
      for (int hc = 0; hc < 2; ++hc) {
        uint32 m1 = 0, m2 = 0;
#pragma unroll
        for (int p = 0; p < 8; ++p) {
          uint32 id = (uint32)((p & 3) | (lg << 2) | ((p >> 2) << 3));
          uint32 pv = (__float_as_uint(acc[m][n][hc * 8 + p]) & ~31u) | id;
          m2 = umax(m2, umin(m1, pv));
          m1 = umax(m1, pv);
        }
        uint32 o1 = (uint32)__shfl_xor((int)m1, 32);
        uint32 o2 = (uint32)__shfl_xor((int)m2, 32);
        m2 = umax(umax(m2, o2), umin(m1, o1));
        m1 = umax(m1, o1);
        float s1 = __uint_as_float(m1 & ~31u);
        float s2 = __uint_as_float(m2 & ~31u);
        res[m * 2 + hc] = (s1 - s2 > SM) ? (m1 | 16u) : m1;
      }
    const int zr = zrowb + wn * 64 + n * 32 + l31;
    uint4 o;  // lg half 0 writes chunks 0..3, half 1 writes 4..7
    o.x = lg ? res[4] : res[0];
    o.y = lg ? res[5] : res[1];
    o.z = lg ? res[6] : res[2];
    o.w = lg ? res[7] : res[3];
    *(uint4*)(bm + (size_t)zr * 512 + cid0 + lg * 4) = o;
  }
}

// ---- Phase 1: bf16 MFMA score GEMM — A-resident LDS, B 2-slot ring ---------
// R11 thesis (from the R0..R10 accounting): gemm tracks glds-staged bytes
// (~10 B/cyc/CU); R3 stages 512 MB (A re-staged 64x, B 8x). Fix: block owns
// 256 codes with FULL K resident in LDS (128 KiB, staged ONCE) and streams
// 2048 zrows through a 2-slot B ring (2x16 KiB). Staging 512 -> 288 MB
// (-44%); loop glds 4 -> 2 per thread-phase. Wave tile / acc[4][2] / MFMA /
// B layout+swizzle / epilogue math: R3-verbatim (re-based indices).
// A layout: [256 codes][256 k], rows of 32 16B-slots; both-sides swizzle
// slot' = g ^ (row&7) (linear glds dest + inverse-swizzled source + swizzled
// read; read quads uniform 8 lanes/quad = the measured b128 floor).
// B ring: chunk c+1 issued at phase-c START into slot (c+1)&1 (sealed by the
// entry barrier: that slot was last read in phase c-1); phase-end vmcnt(0)
// has ~1 full phase of slack (~3000 cyc >> L2 latency) so it is a free seal.
// Grid 256 = 32 cg (256 codes) x 8 yg (2048 rows); 1 block/CU; 64 phases.
__global__ __launch_bounds__(512, 2) void vq_gemm(const ushort* __restrict__ eb,
                                                  const ushort* __restrict__ zb,
                                                  const float* __restrict__ enorm,
                                                  uint32* __restrict__ bm) {
  __shared__ __align__(16) ushort Am[65536];     // 256 codes x 256 k = 128 KiB
  __shared__ __align__(16) ushort Bsr[16384];    // 2 slots x (256 rows x 32 k)
  const int tid = threadIdx.x;
  const int wave = tid >> 6, lane = tid & 63;
  const int wm = wave >> 2, wn = wave & 3;  // wave tile: 128 codes x 64 zrows
  const int l31 = lane & 31, lg = lane >> 5;
  const int cg = blockIdx.x & 31, yg = blockIdx.x >> 5;
  const int code0 = cg * 256;
  const int zrow00 = yg * 2048;   // block's rows: 8 panels of 256
  const int cid0b = cg * 16;      // 16 chunk16s per block

  // ---- A staging (once): 8192 units; unit u: row = u>>5, slot = u&31,
  // global k-group g = (u&31) ^ ((u>>5)&7). 16 glds16/thread, linear dest.
#pragma unroll
  for (int j = 0; j < 16; ++j) {
    const int u = tid + j * 512;
    const int row = u >> 5;
    const int g = (u & 31) ^ (row & 7);
    glds16(eb + (size_t)(code0 + row) * 256 + g * 8,
           Am + (wave * 64 + j * 512) * 8);
  }

  // ---- B staging (R3-verbatim unit scheme): chunk = 1024 units; unit u:
  // row = u>>2, slot = u&3, g = (u&3) ^ ((u>>3)&3). Units tid, tid+512.
  const int u0 = tid, u1 = tid + 512;
  const ushort* bU0 = zb + (size_t)(zrow00 + (u0 >> 2)) * 256 +
                      ((u0 & 3) ^ ((u0 >> 3) & 3)) * 8;
  const ushort* bU1 = zb + (size_t)(zrow00 + (u1 >> 2)) * 256 +
                      ((u1 & 3) ^ ((u1 >> 3) & 3)) * 8;
  ushort* bL = Bsr + wave * 512;  // + slot*8192 (+4096 for unit1); lane*16B HW

  // prologue: B chunk 0 -> slot 0
  glds16(bU0, bL);
  glds16(bU1, bL + 4096);

  asm volatile("s_waitcnt vmcnt(0)" ::: "memory");  // A + B0 resident
  __syncthreads();

  f32x16 acc[4][2];
  init_acc(acc, enorm + code0, wm, lg);

  // read addressing. A: row = wm*128 + m*32 + l31 (row&7 == l31&7); frag
  // (kc,ks) k-group = kc*4 + ks*2 + lg at slot (g ^ (l31&7)). B: R3-verbatim
  // (row>>1)&3 swizzle on 4-slot 64-B rows.
  const int swzA = l31 & 7;
  const int arow = (wm * 128 + l31) * 256;
  const int swzB = (l31 >> 1) & 3;
  const int colu0 = ((0 | lg) ^ swzB) * 8;   // B ks=0
  const int colu1 = ((2 | lg) ^ swzB) * 8;   // B ks=1
  const int brow_u = (wn * 64 + l31) * 32;

#pragma unroll 1
  for (int yp = 0; yp < 8; ++yp) {
    if (yp > 0) {  // finish previous panel; B stream stays in flight
      epilogue(acc, bm, cid0b, zrow00 + (yp - 1) * 256, wm, wn, l31, lg);
      init_acc(acc, enorm + code0, wm, lg);
    }
#pragma unroll
    for (int kc = 0; kc < 8; ++kc) {
      const int c = yp * 8 + kc;
      const int slot = c & 1;
      // 1) issue B chunk c+1 into slot^1 (that slot last read in phase c-1,
      // sealed by the entry barrier)
      if (c < 63) {
        const int cn = c + 1;
        const size_t off = (size_t)(cn >> 3) * 65536 + (size_t)(cn & 7) * 32;
        glds16(bU0 + off, bL + (slot ^ 1) * 8192);
        glds16(bU1 + off, bL + (slot ^ 1) * 8192 + 4096);
      }
      // 2) ds_read 8 A frags (resident) + 4 B frags (sealed prev phase)
      bf16x8 a0[4], a1[4], b0[2], b1[2];
#pragma unroll
      for (int m = 0; m < 4; ++m) {
        a0[m] = *(const bf16x8*)&Am[arow + m * 8192 +
                                    (((kc * 4 + 0) | lg) ^ swzA) * 8];
        a1[m] = *(const bf16x8*)&Am[arow + m * 8192 +
                                    (((kc * 4 + 2) | lg) ^ swzA) * 8];
      }
#pragma unroll
      for (int n = 0; n < 2; ++n) {
        b0[n] = *(const bf16x8*)&Bsr[slot * 8192 + brow_u + n * 1024 + colu0];
        b1[n] = *(const bf16x8*)&Bsr[slot * 8192 + brow_u + n * 1024 + colu1];
      }
      // 3) 16 MFMA (compiler interleaves lgkmcnt(N) with the reads above)
      __builtin_amdgcn_s_setprio(1);
#pragma unroll
      for (int m = 0; m < 4; ++m)
#pragma unroll
        for (int n = 0; n < 2; ++n)
          acc[m][n] = __builtin_amdgcn_mfma_f32_32x32x16_bf16(a0[m], b0[n],
                                                              acc[m][n], 0, 0, 0);
#pragma unroll
      for (int m = 0; m < 4; ++m)
#pragma unroll
        for (int n = 0; n < 2; ++n)
          acc[m][n] = __builtin_amdgcn_mfma_f32_32x32x16_bf16(a1[m], b1[n],
                                                              acc[m][n], 0, 0, 0);
      __builtin_amdgcn_s_setprio(0);
      // 4) seal chunk c+1 (issued a full phase ago -> wait ~free) + barrier
      if (c < 63) {
        asm volatile("s_waitcnt vmcnt(0)" ::: "memory");
        __builtin_amdgcn_s_barrier();
        asm volatile("" ::: "memory");
      }  // c == 63: falls through to the final epilogue (regs only)
    }
  }
  epilogue(acc, bm, cid0b, zrow00 + 7 * 256, wm, wn, l31, lg);
}

// exact fp32 distances for one 16-code chunk; summation order / lane split /
// tie-break bit-identical to the validated slow path.
__device__ __forceinline__ unsigned long long chunk_exact(
    int chunk, const float* __restrict__ zrow, const float* __restrict__ cb,
    const float* __restrict__ enorm, int lane) {
  const int code = chunk * 16 + (lane >> 2);
  const float* zp = zrow + (lane & 3) * 64;
  const float* cp = cb + (size_t)code * 256 + (lane & 3) * 64;
  float s = 0.f;
#pragma unroll
  for (int d = 0; d < 64; d += 4) {
    float4 zv = *(const float4*)(zp + d);
    float4 cv = *(const float4*)(cp + d);
    s = fmaf(zv.x, cv.x, s); s = fmaf(zv.y, cv.y, s);
    s = fmaf(zv.z, cv.z, s); s = fmaf(zv.w, cv.w, s);
  }
  s += __shfl_xor(s, 1);
  s += __shfl_xor(s, 2);
  float dist = fmaf(-2.f, s, enorm[code]);
  unsigned long long key = ((lane & 3) == 0) ? packdi(dist, code) : ~0ull;
#pragma unroll
  for (int m = 1; m < 64; m <<= 1) key = u64min(key, shflx64(key, m));
  return key;  // wave-uniform
}

// ---- Phase 2: one wave per row over 512 chunk16 maxima (validated verbatim) -
__global__ __launch_bounds__(256) void vq_sel(const uint32* __restrict__ bm,
                                              const float* __restrict__ flatz,
                                              const float* __restrict__ cb,
                                              const float* __restrict__ enorm,
                                              float* __restrict__ zq,
                                              float* __restrict__ oidx) {
  const int lane = threadIdx.x & 63;
  const int row = blockIdx.x * 4 + (threadIdx.x >> 6);
  uint4 va = *(const uint4*)(bm + (size_t)row * 512 + lane * 8);
  uint4 vb = *(const uint4*)(bm + (size_t)row * 512 + lane * 8 + 4);
  uint32 v[8] = {va.x, va.y, va.z, va.w, vb.x, vb.y, vb.z, vb.w};
  uint32 m1 = 0, m2 = 0; int ch = 0;
#pragma unroll
  for (int s = 0; s < 8; ++s) {
    uint32 pv = v[s];
    m2 = umax(m2, umin(m1, pv));
    ch = (pv > m1) ? (lane * 8 + s) : ch;
    m1 = umax(m1, pv);
  }
#pragma unroll
  for (int m = 1; m < 64; m <<= 1) {
    uint32 o1 = (uint32)__shfl_xor((int)m1, m);
    uint32 o2 = (uint32)__shfl_xor((int)m2, m);
    int oc = __shfl_xor(ch, m);
    m2 = umax(umax(m2, o2), umin(m1, o1));
    ch = (o1 > m1) ? oc : ch;
    m1 = umax(m1, o1);
  }
  // all wave-uniform now
  float s1 = __uint_as_float(m1 & ~31u);
  float s2 = __uint_as_float(m2 & ~31u);
  int idx;
  if ((m1 & 16u) && (s1 - s2 > SM)) {
    idx = ch * 16 + (int)(m1 & 15u);  // provably the exact argmin
  } else {
    const float* zrow = flatz + (size_t)row * 256;
    unsigned long long key = chunk_exact(ch, zrow, cb, enorm, lane);
    float dbest;
    { unsigned int u = (unsigned int)(key >> 32);
      u = (u & 0x80000000u) ? (u & 0x7FFFFFFFu) : ~u;
      dbest = __uint_as_float(u); }
    float thr = (1024.f - 0.5f * dbest) - EPS_S;  // window lower bound
#pragma unroll
    for (int s = 0; s < 8; ++s) {
      bool cand = __uint_as_float(v[s] & ~31u) >= thr;
      unsigned long long mk = __ballot(cand);
      while (mk) {
        int L = __ffsll(mk) - 1;
        mk &= mk - 1;
        int c2 = L * 8 + s;
        if (c2 == ch) continue;
        key = u64min(key, chunk_exact(c2, zrow, cb, enorm, lane));
      }
    }
    idx = (int)(key & 0xFFFFFFFFull);
  }
  if (lane == 0) oidx[row] = (float)idx;
  float4 val = *(const float4*)(cb + (size_t)idx * 256 + lane * 4);
  *(float4*)(zq + (size_t)row * 256 + lane * 4) = val;  // exact fp32 gather
}

// ---- launch ----------------------------------------------------------------
extern "C" void kernel_launch(void* const* d_in, const int* in_sizes, int n_in,
                              void* d_out, int out_size, void* d_ws, size_t ws_size,
                              hipStream_t stream) {
  const float* z = (const float*)d_in[0];   // (16,256,32,32) fp32
  const float* cb = (const float*)d_in[1];  // (8192,256) fp32
  char* ws = (char*)d_ws;
  // ws: zb 8M@0 | eb 4M@8M | enorm 32K@12M | bm 32M@13M  (45 MB, proven fit)
  ushort* zb = (ushort*)(ws);
  ushort* eb = (ushort*)(ws + (8u << 20));
  float* enorm = (float*)(ws + (12u << 20));
  uint32* bm = (uint32*)(ws + (13u << 20));
  float* zq = (float*)d_out;               // (16384,256) fp32
  float* oidx = zq + (size_t)NROWS * DIM;  // (16384,) as fp32 values
  float* flatz = zq;  // NHWC fp32 z lives in zq until vq_sel overwrites per-row

  prep<<<4096 + NCODES / 4, 256, 0, stream>>>(z, cb, flatz, zb, eb, enorm);
  vq_gemm<<<256, 512, 0, stream>>>(eb, zb, enorm, bm);
  vq_sel<<<NROWS / 4, 256, 0, stream>>>(bm, flatz, cb, enorm, zq, oidx);
}